// Round 7
// baseline (931.480 us; speedup 1.0000x reference)
//
#include <hip/hip_runtime.h>

typedef unsigned short u16;
typedef unsigned int u32;
typedef __attribute__((ext_vector_type(8))) short bf16x8;
typedef __attribute__((ext_vector_type(4))) float f32x4;

#define BZ 16
#define CIN 3
#define C 64
#define N_ 307
#define T_ 24
#define BT (BZ*T_)          // 384
#define ROWS (BT*N_)        // 117888
#define CNT (C*N_*T_)       // 471552

#define OUT_ELEMS 7544832
#define S_ELEMS   36191616

#define HSTRIDE 344         // u16 stride of sHT rows: 688 B = 43*16 (16B-aligned b128)

__device__ __forceinline__ u16 f2b(float v) {
    union { float f; unsigned u; } x; x.f = v;
    unsigned u = x.u;
    unsigned rb = (u >> 16) & 1u;
    u += 0x7fffu + rb;
    return (u16)(u >> 16);
}
__device__ __forceinline__ float wave_sum(float v) {
#pragma unroll
    for (int m = 32; m > 0; m >>= 1) v += __shfl_xor(v, m);
    return v;
}

// ---- kAdjPre: bit-pack adjacency (sup > 0) into adjm[320][10] u32 ----------
__global__ __launch_bounds__(512) void kAdjPre(const float* __restrict__ sup,
        u32* __restrict__ adjm)
{
    int idx = blockIdx.x*512 + threadIdx.x;   // word index: n*10 + kw
    if (idx >= 3200) return;
    int n = idx / 10, kw = idx - n*10;
    u32 bits = 0;
    if (n < N_) {
        const float* row = sup + n*N_ + kw*32;
        int lim = N_ - kw*32; if (lim > 32) lim = 32;
        for (int j = 0; j < lim; ++j)
            if (row[j] > 0.f) bits |= (1u << j);
    }
    adjm[idx] = bits;
}

// ---- phase1: tconv + h = xt@W via MFMA; writes sHT (h^T bf16), sHs, sHd ----
// LDSX=1: x window from LDS (sXw); LDSX=0: x re-read from global (L2-hot).
// W-frags reloaded per tile (keeps VGPR low; W is L2-hot).
template<int LDSX>
__device__ __forceinline__ void phase1_core(
        const float* __restrict__ x, const float* __restrict__ Wg,
        const float* sXw, const float* sTmw, const float* sTmb,
        const float* sUp, const float* sVp,
        u16* sHTp, float* sHsp, float* sHdp,
        int b, int t, int w, int lane)
{
    int l15 = lane & 15, quad = lane >> 4;
#pragma unroll
    for (int ti = 0; ti < 3; ++ti) {
        int mt = w + ti*8;
        if (mt < 20) {
            int row = mt*16 + l15;
            float xv[9];
            if (LDSX) {
#pragma unroll
                for (int ci = 0; ci < 3; ++ci)
#pragma unroll
                for (int k = 0; k < 3; ++k)
                    xv[ci*3 + k] = sXw[(ci*320 + row)*3 + k];
            } else {
                bool rk = row < N_;
                int rc = rk ? row : 0;
#pragma unroll
                for (int ci = 0; ci < 3; ++ci) {
                    const float* xp = x + ((b*CIN + ci)*N_ + rc)*T_ + t;
                    xv[ci*3 + 0] = (rk && t > 0)      ? xp[-1] : 0.f;
                    xv[ci*3 + 1] = rk                 ? xp[0]  : 0.f;
                    xv[ci*3 + 2] = (rk && t < T_ - 1) ? xp[1]  : 0.f;
                }
            }
            float xt[16];
#pragma unroll
            for (int half = 0; half < 2; ++half)
#pragma unroll
            for (int j = 0; j < 8; ++j) {
                int c = half*32 + quad*8 + j;
                float acc = sTmb[c];
#pragma unroll
                for (int ci = 0; ci < 3; ++ci) {
                    const float* wr = &sTmw[(c*3 + ci)*3];
                    acc += wr[0]*xv[ci*3] + wr[1]*xv[ci*3+1] + wr[2]*xv[ci*3+2];
                }
                xt[half*8 + j] = acc > 0.f ? acc : 0.01f*acc;
            }
            // hs/hd dot + cross-quad reduce
            float ps = 0.f, pd = 0.f;
#pragma unroll
            for (int j = 0; j < 8; ++j) {
                ps += xt[j]*sUp[quad*8 + j] + xt[8 + j]*sUp[32 + quad*8 + j];
                pd += xt[j]*sVp[quad*8 + j] + xt[8 + j]*sVp[32 + quad*8 + j];
            }
            ps += __shfl_xor(ps, 16); ps += __shfl_xor(ps, 32);
            pd += __shfl_xor(pd, 16); pd += __shfl_xor(pd, 32);
            if (quad == 0 && row < N_) { sHsp[row] = ps; sHdp[row] = pd; }
            // A-frags
            bf16x8 a0, a1;
#pragma unroll
            for (int j = 0; j < 8; ++j) {
                a0[j] = (short)f2b(xt[j]);
                a1[j] = (short)f2b(xt[8 + j]);
            }
            f32x4 hacc[4];
#pragma unroll
            for (int nt = 0; nt < 4; ++nt) hacc[nt] = (f32x4){0.f,0.f,0.f,0.f};
#pragma unroll
            for (int kk = 0; kk < 2; ++kk) {
                bf16x8 wf[4];
#pragma unroll
                for (int nt = 0; nt < 4; ++nt) {
                    bf16x8 a;
#pragma unroll
                    for (int j = 0; j < 8; ++j)
                        a[j] = (short)f2b(Wg[(kk*32 + quad*8 + j)*64 + nt*16 + l15]);
                    wf[nt] = a;
                }
#pragma unroll
                for (int nt = 0; nt < 4; ++nt)
                    hacc[nt] = __builtin_amdgcn_mfma_f32_16x16x32_bf16(
                        kk ? a1 : a0, wf[nt], hacc[nt], 0, 0, 0);
            }
            // packed u32 stores of h^T
#pragma unroll
            for (int nt = 0; nt < 4; ++nt) {
                u32 w0 = (u32)f2b(hacc[nt][0]) | ((u32)f2b(hacc[nt][1]) << 16);
                u32 w1 = (u32)f2b(hacc[nt][2]) | ((u32)f2b(hacc[nt][3]) << 16);
                u32* dst = (u32*)(sHTp + (nt*16 + l15)*HSTRIDE + mt*16 + quad*4);
                dst[0] = w0; dst[1] = w1;
            }
        }
    }
}

// ---- att_tile: one 16-row attention tile -> unnormalized acc + 1/rowsum ----
__device__ __forceinline__ void att_tile(
        const u32* sAdj, const u16* sHTp, const float* sHsp, const float* sHdp,
        int mt, int l15, int quad, f32x4 acc[4], float* invv_out)
{
    int n = mt*16 + l15;
    float hsv = sHsp[n];
    float asum = 0.f;
#pragma unroll
    for (int nt = 0; nt < 4; ++nt) acc[nt] = (f32x4){0.f,0.f,0.f,0.f};
#pragma unroll
    for (int ks = 0; ks < 10; ++ks) {
        u32 aw = sAdj[n*10 + ks] >> (quad*8);
        int m0 = ks*32 + quad*8;
        bf16x8 a;
#pragma unroll
        for (int j = 0; j < 8; ++j) {
            float e = hsv + sHdp[m0 + j];
            e = e > 0.f ? e : 0.3f*e;
            float ww = ((aw >> j) & 1u) ? __expf(e) : 0.f;
            asum += ww;
            a[j] = (short)f2b(ww);
        }
        const u16* bb = sHTp + m0;
#pragma unroll
        for (int nt = 0; nt < 4; ++nt) {
            bf16x8 bfrag = *(const bf16x8*)(bb + (nt*16 + l15)*HSTRIDE);
            acc[nt] = __builtin_amdgcn_mfma_f32_16x16x32_bf16(a, bfrag, acc[nt], 0, 0, 0);
        }
    }
    asum += __shfl_xor(asum, 16);
    asum += __shfl_xor(asum, 32);
    *invv_out = (asum > 0.f) ? 1.f/asum : 0.f;
}

// ===== kGATF: BOTH GATs fused; filt kept in registers; xg written once ======
// launch_bounds (512,2): round-6's (512,4) capped VGPR at 64 -> fr[] spilled
// to scratch (600 MB HBM traffic, 312us). 128-VGPR cap fits the live set.
__global__ __launch_bounds__(512, 2) void kGATF(
        const float* __restrict__ x,
        const float* __restrict__ tmw, const float* __restrict__ tmb,
        const float* __restrict__ W1, const float* __restrict__ a1s,
        const float* __restrict__ a1d,
        const float* __restrict__ W2, const float* __restrict__ a2s,
        const float* __restrict__ a2d,
        const float* __restrict__ t1w, const float* __restrict__ t2w,
        const u32* __restrict__ adjm,
        float* __restrict__ xg, float* __restrict__ f1,
        float* __restrict__ f2)
{
    __shared__ u16 sHT[64*HSTRIDE];  // 44 KB (reused by both GATs)
    __shared__ float sXA[3200];      // 12.8 KB: x window -> adj mask -> sF2
    __shared__ float sTmw[576];
    __shared__ float sTmb[64];
    __shared__ float sU1[64], sV1[64], sU2[64], sV2[64];
    __shared__ float sHs[320], sHd[320];

    int bt = blockIdx.x;
    int b = bt / T_, t = bt - b * T_;
    int tid = threadIdx.x;
    int w = tid >> 6, lane = tid & 63;
    int l15 = lane & 15, quad = lane >> 4;

    // ---- stage x window + weights ----
    for (int i = tid; i < 2880; i += 512) {
        int k = i % 3; int rest = i / 3;
        int n = rest % 320; int ci = rest / 320;
        int tt = t - 1 + k;
        float v = 0.f;
        if (n < N_ && tt >= 0 && tt < T_)
            v = x[((b*CIN + ci)*N_ + n)*T_ + tt];
        sXA[i] = v;
    }
    for (int i = tid; i < 576; i += 512) sTmw[i] = tmw[i];
    if (tid < 128) {
        int c = tid & 63;
        const float* Wp = (tid < 64) ? W1 : W2;
        const float* sp = (tid < 64) ? a1s : a2s;
        const float* dp = (tid < 64) ? a1d : a2d;
        float u = 0.f, v = 0.f;
#pragma unroll
        for (int f4 = 0; f4 < 16; ++f4) {
            float4 wr = ((const float4*)(Wp + c*64))[f4];
            float4 s4 = ((const float4*)sp)[f4];
            float4 d4 = ((const float4*)dp)[f4];
            u += wr.x*s4.x + wr.y*s4.y + wr.z*s4.z + wr.w*s4.w;
            v += wr.x*d4.x + wr.y*d4.y + wr.z*d4.z + wr.w*d4.w;
        }
        if (tid < 64) { sU1[c] = u; sV1[c] = v; sTmb[c] = tmb[c]; }
        else          { sU2[c] = u; sV2[c] = v; }
    }
    __syncthreads();

    // ---- GAT1 phase 1 (x from LDS) ----
    phase1_core<1>(x, W1, sXA, sTmw, sTmb, sU1, sV1, sHT, sHs, sHd, b, t, w, lane);
    if (tid < 13) { sHs[307+tid] = -700.f; sHd[307+tid] = -700.f; }
    __syncthreads();

    // ---- adj bitmask into LDS (overwrites x window) ----
    u32* sAdj = (u32*)sXA;
    for (int i = tid; i < 3200; i += 512) sAdj[i] = adjm[i];
    __syncthreads();

    // ---- GAT1 phase 2 -> filt kept in registers ----
    float fr[3][4][4];
#pragma unroll
    for (int ti = 0; ti < 3; ++ti) {
        int mt = w + ti*8;
        if (mt < 20) {
            f32x4 acc[4]; float invv;
            att_tile(sAdj, sHT, sHs, sHd, mt, l15, quad, acc, &invv);
#pragma unroll
            for (int nt = 0; nt < 4; ++nt)
#pragma unroll
            for (int reg = 0; reg < 4; ++reg) {
                float inv2 = __shfl(invv, quad*4 + reg);
                fr[ti][nt][reg] = acc[nt][reg] * inv2;
            }
        }
    }
    __syncthreads();   // before sHT/sHs/sHd rewrite

    // ---- GAT2 phase 1 (x from global; L2-hot) ----
    phase1_core<0>(x, W2, nullptr, sTmw, sTmb, sU2, sV2, sHT, sHs, sHd, b, t, w, lane);
    // pad rows 307..319 persist from GAT1
    __syncthreads();

    // ---- GAT2 phase 2 + gating epilogue ----
    float t1all[4];
#pragma unroll
    for (int nt = 0; nt < 4; ++nt) t1all[nt] = t1w[nt*16 + l15];
    float q[4] = {0,0,0,0};

#pragma unroll
    for (int ti = 0; ti < 3; ++ti) {
        int mt = w + ti*8;
        if (mt < 20) {
            f32x4 acc[4]; float invv;
            att_tile(sAdj, sHT, sHs, sHd, mt, l15, quad, acc, &invv);
            float p[4] = {0,0,0,0};
#pragma unroll
            for (int nt = 0; nt < 4; ++nt) {
                int c = nt*16 + l15;
#pragma unroll
                for (int reg = 0; reg < 4; ++reg) {
                    int n2 = mt*16 + quad*4 + reg;
                    float inv2 = __shfl(invv, quad*4 + reg);
                    float gate = acc[nt][reg] * inv2;
                    float gt = 1.f / (1.f + __expf(-gate));
                    float fv = fr[ti][nt][reg];
                    fv = fv > 0.f ? fv : 0.01f*fv;
                    float xv = gt * fv;
                    size_t idx = (size_t)(bt*N_ + n2)*64 + c;
                    if (n2 < N_) xg[idx] = xv; else xv = 0.f;
                    p[reg] += xv * t1all[nt];
                    float t2v = (n2 < N_) ? t2w[n2] : 0.f;
                    q[nt] += xv * t2v;
                }
            }
#pragma unroll
            for (int reg = 0; reg < 4; ++reg) {
                float s = p[reg];
                s += __shfl_xor(s, 1); s += __shfl_xor(s, 2);
                s += __shfl_xor(s, 4); s += __shfl_xor(s, 8);
                int n2 = mt*16 + quad*4 + reg;
                if (l15 == 0 && n2 < N_) f1[bt*N_ + n2] = s;
            }
        }
    }
    __syncthreads();   // sAdj dead; reuse sXA as sF2
    float* sF2 = sXA;
#pragma unroll
    for (int nt = 0; nt < 4; ++nt) {
        float s = q[nt];
        s += __shfl_xor(s, 16); s += __shfl_xor(s, 32);
        if (quad == 0) sF2[w*64 + nt*16 + l15] = s;
    }
    __syncthreads();
    if (tid < 64) {
        float s = sF2[tid];
#pragma unroll
        for (int ww = 1; ww < 8; ++ww) s += sF2[ww*64 + tid];
        f2[(b*C + tid)*T_ + t] = s;
    }
}

// ===== kSc: recompute GAT1 softmax and write S_coef (runs LAST) ==============
__global__ __launch_bounds__(512) void kSc(
        const float* __restrict__ x, const float* __restrict__ sup,
        const float* __restrict__ tmw, const float* __restrict__ tmb,
        const float* __restrict__ W, const float* __restrict__ asp,
        const float* __restrict__ adp, float* __restrict__ Sc)
{
    __shared__ float sHs[320];
    __shared__ float sHd[320];
    __shared__ float sU[64], sV[64];
    __shared__ float sTmw[576];
    __shared__ float sTmb[64];

    int half = blockIdx.x;
    int bt = blockIdx.y;
    int b = bt / T_, t = bt - b * T_;
    int tid = threadIdx.x;
    int w = tid >> 6, lane = tid & 63;

    for (int i = tid; i < 576; i += 512) sTmw[i] = tmw[i];
    if (tid < 64) {
        sTmb[tid] = tmb[tid];
        float u = 0.f, v = 0.f;
#pragma unroll
        for (int f4 = 0; f4 < 16; ++f4) {
            float4 wr = ((const float4*)(W + tid*64))[f4];
            float4 s4 = ((const float4*)asp)[f4];
            float4 d4 = ((const float4*)adp)[f4];
            u += wr.x*s4.x + wr.y*s4.y + wr.z*s4.z + wr.w*s4.w;
            v += wr.x*d4.x + wr.y*d4.y + wr.z*d4.z + wr.w*d4.w;
        }
        sU[tid] = u; sV[tid] = v;
    }
    __syncthreads();

    if (tid < 320) {
        int n = tid;
        if (n >= N_) { sHs[n] = -700.f; sHd[n] = -700.f; }
        else {
            float xv[3][3];
#pragma unroll
            for (int ci = 0; ci < 3; ++ci) {
                const float* xp = x + ((b*CIN + ci)*N_ + n)*T_ + t;
                xv[ci][0] = (t > 0)      ? xp[-1] : 0.f;
                xv[ci][1] = xp[0];
                xv[ci][2] = (t < T_ - 1) ? xp[1]  : 0.f;
            }
            float hs = 0.f, hd = 0.f;
#pragma unroll
            for (int c = 0; c < 64; ++c) {
                float acc = sTmb[c];
#pragma unroll
                for (int ci = 0; ci < 3; ++ci) {
                    const float* wr = &sTmw[(c*3 + ci)*3];
                    acc += wr[0]*xv[ci][0] + wr[1]*xv[ci][1] + wr[2]*xv[ci][2];
                }
                float xt = acc > 0.f ? acc : 0.01f*acc;
                hs += xt * sU[c];
                hd += xt * sV[c];
            }
            sHs[n] = hs; sHd[n] = hd;
        }
    }
    __syncthreads();

    int base = half ? 154 : 0;
    int cnt  = half ? 153 : 154;
#pragma unroll 1
    for (int r = w; r < cnt; r += 8) {
        int n = base + r;
        float hsv = sHs[n];
        const float* srow = sup + n*N_;
        float ww0, ww1, ww2, ww3, ww4;
        {
            float e;
            ww0 = 0.f;
            if (srow[lane] > 0.f) { e = hsv + sHd[lane]; e = e > 0.f ? e : 0.3f*e; ww0 = __expf(e); }
            ww1 = 0.f;
            if (srow[64 + lane] > 0.f) { e = hsv + sHd[64 + lane]; e = e > 0.f ? e : 0.3f*e; ww1 = __expf(e); }
            ww2 = 0.f;
            if (srow[128 + lane] > 0.f) { e = hsv + sHd[128 + lane]; e = e > 0.f ? e : 0.3f*e; ww2 = __expf(e); }
            ww3 = 0.f;
            if (srow[192 + lane] > 0.f) { e = hsv + sHd[192 + lane]; e = e > 0.f ? e : 0.3f*e; ww3 = __expf(e); }
            ww4 = 0.f;
            if (256 + lane < N_ && srow[256 + lane] > 0.f) {
                e = hsv + sHd[256 + lane]; e = e > 0.f ? e : 0.3f*e; ww4 = __expf(e);
            }
        }
        float asum = wave_sum(ww0 + ww1 + ww2 + ww3 + ww4);
        float inv = (asum > 0.f) ? 1.f/asum : 0.f;
        float* drow = Sc + (size_t)(bt*N_ + n)*N_;
        drow[lane]       = ww0*inv;
        drow[64 + lane]  = ww1*inv;
        drow[128 + lane] = ww2*inv;
        drow[192 + lane] = ww3*inv;
        if (256 + lane < N_) drow[256 + lane] = ww4*inv;
    }
}

// ---------------- kD0: g1[bt][c] = sum_n f1[bt][n] * tw[n][c] ----------------
__global__ __launch_bounds__(256) void kD0(const float* __restrict__ f1,
        const float* __restrict__ tw, float* __restrict__ g1)
{
    __shared__ float part[4][64];
    int bt = blockIdx.x;
    int w = threadIdx.x >> 6, lane = threadIdx.x & 63;
    float acc = 0.f;
    for (int n = w*77; n < (w+1)*77 && n < N_; ++n)
        acc += f1[bt*N_ + n] * tw[n*64 + lane];
    part[w][lane] = acc;
    __syncthreads();
    if (threadIdx.x < 64) {
        float s = part[0][threadIdx.x] + part[1][threadIdx.x]
                + part[2][threadIdx.x] + part[3][threadIdx.x];
        g1[bt*64 + threadIdx.x] = s;
    }
}

// ---------------- kD: temporal attention TATT_1 ------------------------------
__global__ __launch_bounds__(256) void kD(const float* __restrict__ g1,
        const float* __restrict__ f2, const float* __restrict__ tb,
        const float* __restrict__ tv,
        const float* __restrict__ bng, const float* __restrict__ bnb,
        float* __restrict__ coefs, float* __restrict__ Tc,
        float* __restrict__ stats)
{
    __shared__ float g1s[T_][C];
    __shared__ float f2s[C][T_];
    __shared__ float lg[T_][T_];
    __shared__ float l2[T_][T_];
    int b = blockIdx.x, tid = threadIdx.x;
    if (tid == 0) { stats[2*b] = 0.f; stats[2*b + 1] = 0.f; }
    for (int idx = tid; idx < T_*C; idx += 256) {
        int t = idx / C, c = idx - t*C;
        g1s[t][c] = g1[(b*T_ + t)*C + c];
        int c2 = idx / T_, t2 = idx - c2*T_;
        f2s[c2][t2] = f2[(b*C + c2)*T_ + t2];
    }
    __syncthreads();
    for (int idx = tid; idx < T_*T_; idx += 256) {
        int t = idx / T_, q = idx - t*T_;
        float s = 0.f;
#pragma unroll
        for (int c = 0; c < C; ++c) s += g1s[t][c] * f2s[c][q];
        s += tb[t*T_ + q];
        lg[t][q] = 1.f / (1.f + expf(-s));
    }
    __syncthreads();
    const float bnscale = 0.99999500003749972f;  // 1/sqrt(1+1e-5)
    for (int idx = tid; idx < T_*T_; idx += 256) {
        int p = idx / T_, q = idx - p*T_;
        float s = 0.f;
#pragma unroll
        for (int t = 0; t < T_; ++t) s += tv[p*T_ + t] * lg[t][q];
        s = s * bnscale * bng[q] + bnb[q];
        if (q > p) s += -1e13f;   // causal mask
        l2[p][q] = s;
    }
    __syncthreads();
    if (tid < T_) {
        int p = tid;
        float mx = -3e38f;
#pragma unroll
        for (int q = 0; q < T_; ++q) mx = fmaxf(mx, l2[p][q]);
        float e[T_]; float sum = 0.f;
#pragma unroll
        for (int q = 0; q < T_; ++q) { e[q] = expf(l2[p][q] - mx); sum += e[q]; }
        float inv = 1.f / sum;
#pragma unroll
        for (int q = 0; q < T_; ++q) {
            float v = e[q] * inv;
            coefs[(b*T_ + p)*T_ + q] = v;
            Tc[(b*T_ + q)*T_ + p] = v;
        }
    }
}

// ---------------- kE: temporal mix + residual + LayerNorm --------------------
__device__ __forceinline__ void compute_y(int b, int n, int lane,
        const float* __restrict__ xg, const float cf[T_][T_],
        const float* __restrict__ x, const float* __restrict__ c1w,
        const float* __restrict__ c1b, float* y)
{
    float acc[T_];
#pragma unroll
    for (int q = 0; q < T_; ++q) acc[q] = 0.f;
#pragma unroll 1
    for (int l = 0; l < T_; ++l) {
        float xv = xg[(size_t)((b*T_ + l)*N_ + n)*64 + lane];
#pragma unroll
        for (int q = 0; q < T_; ++q) acc[q] += xv * cf[q][l];
    }
    float w0 = c1w[lane*3+0], w1 = c1w[lane*3+1], w2 = c1w[lane*3+2];
    float bb = c1b[lane];
    const float* xb0 = x + ((b*CIN + 0)*N_ + n)*T_;
    const float* xb1 = x + ((b*CIN + 1)*N_ + n)*T_;
    const float* xb2 = x + ((b*CIN + 2)*N_ + n)*T_;
#pragma unroll
    for (int q = 0; q < T_; ++q) {
        float xin = bb + w0*xb0[q] + w1*xb1[q] + w2*xb2[q];
        float v = acc[q];
        v = v > 0.f ? v : 0.01f*v;
        y[q] = v + xin;
    }
}

__global__ __launch_bounds__(256) void kE1(const float* __restrict__ xg,
        const float* __restrict__ coefs, const float* __restrict__ x,
        const float* __restrict__ c1w, const float* __restrict__ c1b,
        float* __restrict__ stats)
{
    __shared__ float cf[T_][T_];
    int b = blockIdx.y;
    for (int i = threadIdx.x; i < T_*T_; i += 256) ((float*)cf)[i] = coefs[b*T_*T_ + i];
    __syncthreads();
    int w = threadIdx.x >> 6, lane = threadIdx.x & 63;
    int n = blockIdx.x*4 + w;
    if (n >= N_) return;
    float y[T_];
    compute_y(b, n, lane, xg, cf, x, c1w, c1b, y);
    float s = 0.f, ss = 0.f;
#pragma unroll
    for (int q = 0; q < T_; ++q) { s += y[q]; ss += y[q]*y[q]; }
    s = wave_sum(s); ss = wave_sum(ss);
    if (lane == 0) { atomicAdd(&stats[2*b], s); atomicAdd(&stats[2*b + 1], ss); }
}

__global__ __launch_bounds__(256) void kE2(const float* __restrict__ xg,
        const float* __restrict__ coefs, const float* __restrict__ x,
        const float* __restrict__ c1w, const float* __restrict__ c1b,
        const float* __restrict__ stats, const float* __restrict__ lnw,
        const float* __restrict__ lnb, float* __restrict__ out)
{
    __shared__ float cf[T_][T_];
    int b = blockIdx.y;
    for (int i = threadIdx.x; i < T_*T_; i += 256) ((float*)cf)[i] = coefs[b*T_*T_ + i];
    __syncthreads();
    int w = threadIdx.x >> 6, lane = threadIdx.x & 63;
    int n = blockIdx.x*4 + w;
    if (n >= N_) return;
    float y[T_];
    compute_y(b, n, lane, xg, cf, x, c1w, c1b, y);
    float mu   = stats[2*b] * (1.f/CNT);
    float var  = stats[2*b + 1] * (1.f/CNT) - mu*mu;
    float rstd = rsqrtf(fmaxf(var, 0.f) + 1e-5f);
    int gi = (lane*N_ + n)*T_;
    float ov[T_];
#pragma unroll
    for (int q = 0; q < T_; ++q)
        ov[q] = (y[q] - mu)*rstd*lnw[gi + q] + lnb[gi + q];
    float* dst = out + ((size_t)(b*C + lane)*N_ + n)*T_;
#pragma unroll
    for (int j = 0; j < 6; ++j) {
        float4 v;
        v.x = ov[j*4+0]; v.y = ov[j*4+1]; v.z = ov[j*4+2]; v.w = ov[j*4+3];
        ((float4*)dst)[j] = v;
    }
}

extern "C" void kernel_launch(void* const* d_in, const int* in_sizes, int n_in,
                              void* d_out, int out_size, void* d_ws, size_t ws_size,
                              hipStream_t stream)
{
    const float* x   = (const float*)d_in[0];
    const float* sup = (const float*)d_in[1];
    const float* c1w = (const float*)d_in[2];
    const float* c1b = (const float*)d_in[3];
    const float* tmw = (const float*)d_in[4];
    const float* tmb = (const float*)d_in[5];
    const float* W1  = (const float*)d_in[6];
    const float* a1s = (const float*)d_in[7];
    const float* a1d = (const float*)d_in[8];
    const float* W2  = (const float*)d_in[9];
    const float* a2s = (const float*)d_in[10];
    const float* a2d = (const float*)d_in[11];
    const float* t1w = (const float*)d_in[12];
    const float* t2w = (const float*)d_in[13];
    const float* tw  = (const float*)d_in[14];
    const float* tb  = (const float*)d_in[15];
    const float* tv  = (const float*)d_in[16];
    const float* bng = (const float*)d_in[17];
    const float* bnb = (const float*)d_in[18];
    const float* lnw = (const float*)d_in[19];
    const float* lnb = (const float*)d_in[20];

    float* out = (float*)d_out;
    float* Sc  = out + OUT_ELEMS;               // final S_coef region (f32)
    float* Tc  = Sc + (size_t)S_ELEMS;          // final T_coef region (f32)

    // ALL scratch lives inside the Sc region (overwritten last by kSc).
    // d_ws is never touched.
    float* xg    = Sc;                          // OUT_ELEMS f32 (gated GAT output)
    float* f1    = Sc + (size_t)OUT_ELEMS;      // ROWS f32
    float* f2    = f1 + ROWS;                   // BZ*C*T_ f32
    float* g1    = f2 + BZ*C*T_;                // BT*C f32
    float* coefs = g1 + BT*C;                   // BZ*T_*T_ f32
    float* stats = coefs + BZ*T_*T_;            // 32 f32
    u32*   adjm  = (u32*)(stats + 32);          // 3200 u32 adjacency bitmask

    kAdjPre<<<7, 512, 0, stream>>>(sup, adjm);
    kGATF<<<BT, 512, 0, stream>>>(x, tmw, tmb, W1, a1s, a1d, W2, a2s, a2d,
                                  t1w, t2w, adjm, xg, f1, f2);
    kD0<<<BT, 256, 0, stream>>>(f1, tw, g1);
    kD<<<BZ, 256, 0, stream>>>(g1, f2, tb, tv, bng, bnb, coefs, Tc, stats);
    kE1<<<dim3(77, BZ), 256, 0, stream>>>(xg, coefs, x, c1w, c1b, stats);
    kE2<<<dim3(77, BZ), 256, 0, stream>>>(xg, coefs, x, c1w, c1b, stats, lnw, lnb, out);
    kSc<<<dim3(2, BT), 512, 0, stream>>>(x, sup, tmw, tmb, W1, a1s, a1d, Sc);
}

// Round 8
// 591.102 us; speedup vs baseline: 1.5758x; 1.5758x over previous
//
#include <hip/hip_runtime.h>

typedef unsigned short u16;
typedef unsigned int u32;
typedef __attribute__((ext_vector_type(8))) short bf16x8;
typedef __attribute__((ext_vector_type(4))) float f32x4;

#define BZ 16
#define CIN 3
#define C 64
#define N_ 307
#define T_ 24
#define BT (BZ*T_)          // 384
#define ROWS (BT*N_)        // 117888
#define CNT (C*N_*T_)       // 471552

#define OUT_ELEMS 7544832
#define S_ELEMS   36191616

#define HSTRIDE 344         // u16 stride of sHT rows: 688 B = 43*16 (16B-aligned b128)

__device__ __forceinline__ u16 f2b(float v) {
    union { float f; unsigned u; } x; x.f = v;
    unsigned u = x.u;
    unsigned rb = (u >> 16) & 1u;
    u += 0x7fffu + rb;
    return (u16)(u >> 16);
}
__device__ __forceinline__ float wave_sum(float v) {
#pragma unroll
    for (int m = 32; m > 0; m >>= 1) v += __shfl_xor(v, m);
    return v;
}

// ---- kAdjPre: bit-pack adjacency (sup > 0) into adjm[320][10] u32 ----------
__global__ __launch_bounds__(512) void kAdjPre(const float* __restrict__ sup,
        u32* __restrict__ adjm)
{
    int idx = blockIdx.x*512 + threadIdx.x;   // word index: n*10 + kw
    if (idx >= 3200) return;
    int n = idx / 10, kw = idx - n*10;
    u32 bits = 0;
    if (n < N_) {
        const float* row = sup + n*N_ + kw*32;
        int lim = N_ - kw*32; if (lim > 32) lim = 32;
        for (int j = 0; j < lim; ++j)
            if (row[j] > 0.f) bits |= (1u << j);
    }
    adjm[idx] = bits;
}

// ===== kGAT2: both GATs in ONE dispatch, grid (BT, 2) ========================
// blockIdx.y = 0: GAT1 -> writes normalized filt to fbuf
// blockIdx.y = 1: GAT2 -> writes normalized gate LOGIT to gbuf
// (round-5 proven per-block structure: 512 thr, wf preloaded, af[10] pass;
//  decoupling removes the agbuf read-dependency -> single 768-block launch)
__global__ __launch_bounds__(512, 2) void kGAT2(
        const float* __restrict__ x,
        const float* __restrict__ tmw, const float* __restrict__ tmb,
        const float* __restrict__ W1, const float* __restrict__ a1s,
        const float* __restrict__ a1d,
        const float* __restrict__ W2, const float* __restrict__ a2s,
        const float* __restrict__ a2d,
        const u32* __restrict__ adjm,
        float* __restrict__ fbuf, float* __restrict__ gbuf)
{
    __shared__ u16 sHT[64*HSTRIDE];  // 44 KB, h transposed [f][m] bf16
    __shared__ float sXA[3200];      // 12.8 KB: x window -> adj bitmask
    __shared__ float sTmw[576];
    __shared__ float sTmb[64];
    __shared__ float sU[64];
    __shared__ float sV[64];
    __shared__ float sHs[320];
    __shared__ float sHd[320];

    int bt = blockIdx.x;
    int gy = blockIdx.y;
    int b = bt / T_, t = bt - b * T_;
    int tid = threadIdx.x;
    int w = tid >> 6, lane = tid & 63;
    int l15 = lane & 15, quad = lane >> 4;

    const float* W   = gy ? W2  : W1;
    const float* asp = gy ? a2s : a1s;
    const float* adp = gy ? a2d : a1d;
    float* dst       = gy ? gbuf : fbuf;

    // ---- stage x window + weights ----
    for (int i = tid; i < 2880; i += 512) {
        int k = i % 3; int rest = i / 3;
        int n = rest % 320; int ci = rest / 320;
        int tt = t - 1 + k;
        float v = 0.f;
        if (n < N_ && tt >= 0 && tt < T_)
            v = x[((b*CIN + ci)*N_ + n)*T_ + tt];
        sXA[i] = v;
    }
    for (int i = tid; i < 576; i += 512) sTmw[i] = tmw[i];
    if (tid < 64) {
        sTmb[tid] = tmb[tid];
        // u[c] = W[c]·a_src, v[c] = W[c]·a_dst (f32)
        float u = 0.f, v = 0.f;
#pragma unroll
        for (int f4 = 0; f4 < 16; ++f4) {
            float4 wr = ((const float4*)(W + tid*64))[f4];
            float4 s4 = ((const float4*)asp)[f4];
            float4 d4 = ((const float4*)adp)[f4];
            u += wr.x*s4.x + wr.y*s4.y + wr.z*s4.z + wr.w*s4.w;
            v += wr.x*d4.x + wr.y*d4.y + wr.z*d4.z + wr.w*d4.w;
        }
        sU[tid] = u; sV[tid] = v;
    }

    // W as MFMA B-frags: wf[kk][nt][j] = W[kk*32+quad*8+j][nt*16+l15]
    bf16x8 wf[2][4];
#pragma unroll
    for (int kk = 0; kk < 2; ++kk)
#pragma unroll
    for (int nt = 0; nt < 4; ++nt) {
        bf16x8 a;
#pragma unroll
        for (int j = 0; j < 8; ++j)
            a[j] = (short)f2b(W[(kk*32 + quad*8 + j)*64 + nt*16 + l15]);
        wf[kk][nt] = a;
    }
    __syncthreads();

    // ---- phase 1: tconv + h via MFMA; sHT, sHs, sHd ----
#pragma unroll 1
    for (int mt = w; mt < 20; mt += 8) {
        int row = mt*16 + l15;
        float xt[16];
#pragma unroll
        for (int half = 0; half < 2; ++half) {
#pragma unroll
            for (int j = 0; j < 8; ++j) {
                int c = half*32 + quad*8 + j;
                float acc = sTmb[c];
#pragma unroll
                for (int ci = 0; ci < 3; ++ci) {
                    const float* xr = &sXA[(ci*320 + row)*3];
                    const float* wr = &sTmw[(c*3 + ci)*3];
                    acc += wr[0]*xr[0] + wr[1]*xr[1] + wr[2]*xr[2];
                }
                xt[half*8 + j] = acc > 0.f ? acc : 0.01f*acc;
            }
        }
        // hs/hd: f32 dot with u,v then cross-quad reduce
        float ps = 0.f, pd = 0.f;
#pragma unroll
        for (int j = 0; j < 8; ++j) {
            ps += xt[j]*sU[quad*8 + j] + xt[8 + j]*sU[32 + quad*8 + j];
            pd += xt[j]*sV[quad*8 + j] + xt[8 + j]*sV[32 + quad*8 + j];
        }
        ps += __shfl_xor(ps, 16); ps += __shfl_xor(ps, 32);
        pd += __shfl_xor(pd, 16); pd += __shfl_xor(pd, 32);
        if (quad == 0 && row < N_) { sHs[row] = ps; sHd[row] = pd; }
        // A-frags + h MFMA
        bf16x8 a0, a1;
#pragma unroll
        for (int j = 0; j < 8; ++j) {
            a0[j] = (short)f2b(xt[j]);
            a1[j] = (short)f2b(xt[8 + j]);
        }
        f32x4 hacc[4];
#pragma unroll
        for (int nt = 0; nt < 4; ++nt) {
            f32x4 z = {0.f, 0.f, 0.f, 0.f};
            z = __builtin_amdgcn_mfma_f32_16x16x32_bf16(a0, wf[0][nt], z, 0, 0, 0);
            z = __builtin_amdgcn_mfma_f32_16x16x32_bf16(a1, wf[1][nt], z, 0, 0, 0);
            hacc[nt] = z;
        }
        // write h^T: f = nt*16+l15, m = mt*16+quad*4+reg (packed u32)
#pragma unroll
        for (int nt = 0; nt < 4; ++nt) {
            u32 w0 = (u32)f2b(hacc[nt][0]) | ((u32)f2b(hacc[nt][1]) << 16);
            u32 w1 = (u32)f2b(hacc[nt][2]) | ((u32)f2b(hacc[nt][3]) << 16);
            u32* dp = (u32*)(sHT + (nt*16 + l15)*HSTRIDE + mt*16 + quad*4);
            dp[0] = w0; dp[1] = w1;
        }
    }
    if (tid < 13) { sHs[307+tid] = -700.f; sHd[307+tid] = -700.f; }
    __syncthreads();   // phase 1 done with sXA

    // ---- adj bitmask into LDS (overwrites x window) ----
    u32* sAdj = (u32*)sXA;
    for (int i = tid; i < 3200; i += 512) sAdj[i] = adjm[i];
    __syncthreads();

    // ---- phase 2: A-frag generation + MFMA att@h; write normalized out ----
#pragma unroll 1
    for (int mt = w; mt < 20; mt += 8) {
        int n = mt*16 + l15;                 // A row owned by this lane
        float hsv = sHs[n];
        float asum = 0.f;
        bf16x8 af[10];
#pragma unroll
        for (int ks = 0; ks < 10; ++ks) {
            u32 aw = sAdj[n*10 + ks] >> (quad*8);
            int m0 = ks*32 + quad*8;
            bf16x8 a;
#pragma unroll
            for (int j = 0; j < 8; ++j) {
                float e = hsv + sHd[m0 + j];
                e = e > 0.f ? e : 0.3f*e;
                float ww = ((aw >> j) & 1u) ? __expf(e) : 0.f;
                asum += ww;
                a[j] = (short)f2b(ww);
            }
            af[ks] = a;
        }
        asum += __shfl_xor(asum, 16);
        asum += __shfl_xor(asum, 32);
        float invv = (asum > 0.f) ? 1.f/asum : 0.f;

#pragma unroll 1
        for (int nt = 0; nt < 4; ++nt) {
            f32x4 acc = {0.f, 0.f, 0.f, 0.f};
            const u16* bbase = sHT + (nt*16 + l15)*HSTRIDE;
#pragma unroll
            for (int ks = 0; ks < 10; ++ks) {
                bf16x8 bfrag = *(const bf16x8*)(bbase + ks*32 + quad*8);
                acc = __builtin_amdgcn_mfma_f32_16x16x32_bf16(af[ks], bfrag, acc, 0, 0, 0);
            }
            int c = nt*16 + l15;
#pragma unroll
            for (int reg = 0; reg < 4; ++reg) {
                int n2 = mt*16 + quad*4 + reg;       // C-layout row
                float inv2 = __shfl(invv, quad*4 + reg);
                float a = acc[reg] * inv2;
                if (n2 < N_) dst[(size_t)(bt*N_ + n2)*64 + c] = a;
            }
        }
    }
}

// ===== kComb: xv = sigmoid(gate)*lrelu(filt) in-place; f1, f2, g1 ===========
// 512 threads, block per bt. fbuf aliases xg (in-place elementwise update).
__global__ __launch_bounds__(512) void kComb(
        float* __restrict__ xg, const float* __restrict__ gbuf,
        const float* __restrict__ t1w, const float* __restrict__ t2w,
        const float* __restrict__ tw,
        float* __restrict__ f1, float* __restrict__ f2,
        float* __restrict__ g1)
{
    __shared__ float sF1[320];
    __shared__ float sRed[8][64];
    __shared__ float sT1[64];

    int bt = blockIdx.x;
    int b = bt / T_, t = bt - b * T_;
    int tid = threadIdx.x;
    int w = tid >> 6, lane = tid & 63;

    if (tid < 64) sT1[tid] = t1w[tid];
    if (tid < 13) sF1[307 + tid] = 0.f;
    __syncthreads();

    float f2acc = 0.f;
#pragma unroll 1
    for (int n = w; n < N_; n += 8) {
        size_t idx = (size_t)(bt*N_ + n)*64 + lane;
        float f = xg[idx];            // filt (fbuf)
        float g = gbuf[idx];          // gate logit
        float gt = 1.f / (1.f + __expf(-g));
        float fv = f > 0.f ? f : 0.01f*f;
        float xv = gt * fv;
        xg[idx] = xv;                 // in-place
        float p = wave_sum(xv * sT1[lane]);
        if (lane == 0) sF1[n] = p;
        f2acc += xv * t2w[n];
    }
    __syncthreads();
    // f2[c] = sum over n (cross-wave)
    sRed[w][lane] = f2acc;
    __syncthreads();
    if (tid < 64) {
        float s = sRed[0][tid];
#pragma unroll
        for (int ww = 1; ww < 8; ++ww) s += sRed[ww][tid];
        f2[(b*C + tid)*T_ + t] = s;
        // also publish f1 to global (needed? only g1 consumes f1; skip global f1)
    }
    if (tid < 320 && tid < N_) f1[bt*N_ + tid] = sF1[tid];
    __syncthreads();
    // g1[bt][c] = sum_n sF1[n] * tw[n][c], spread over 8 waves
    float gacc = 0.f;
    int n0 = w*40, n1 = n0 + 40; if (n1 > N_) n1 = N_;
    for (int n = n0; n < n1; ++n) gacc += sF1[n] * tw[n*64 + lane];
    sRed[w][lane] = gacc;
    __syncthreads();
    if (tid < 64) {
        float s = sRed[0][tid];
#pragma unroll
        for (int ww = 1; ww < 8; ++ww) s += sRed[ww][tid];
        g1[bt*64 + tid] = s;
    }
}

// ===== kSc: recompute GAT1 softmax and write S_coef (runs LAST) ==============
__global__ __launch_bounds__(512) void kSc(
        const float* __restrict__ x, const float* __restrict__ sup,
        const float* __restrict__ tmw, const float* __restrict__ tmb,
        const float* __restrict__ W, const float* __restrict__ asp,
        const float* __restrict__ adp, float* __restrict__ Sc)
{
    __shared__ float sHs[320];
    __shared__ float sHd[320];
    __shared__ float sU[64], sV[64];
    __shared__ float sTmw[576];
    __shared__ float sTmb[64];

    int half = blockIdx.x;
    int bt = blockIdx.y;
    int b = bt / T_, t = bt - b * T_;
    int tid = threadIdx.x;
    int w = tid >> 6, lane = tid & 63;

    for (int i = tid; i < 576; i += 512) sTmw[i] = tmw[i];
    if (tid < 64) {
        sTmb[tid] = tmb[tid];
        float u = 0.f, v = 0.f;
#pragma unroll
        for (int f4 = 0; f4 < 16; ++f4) {
            float4 wr = ((const float4*)(W + tid*64))[f4];
            float4 s4 = ((const float4*)asp)[f4];
            float4 d4 = ((const float4*)adp)[f4];
            u += wr.x*s4.x + wr.y*s4.y + wr.z*s4.z + wr.w*s4.w;
            v += wr.x*d4.x + wr.y*d4.y + wr.z*d4.z + wr.w*d4.w;
        }
        sU[tid] = u; sV[tid] = v;
    }
    __syncthreads();

    if (tid < 320) {
        int n = tid;
        if (n >= N_) { sHs[n] = -700.f; sHd[n] = -700.f; }
        else {
            float xv[3][3];
#pragma unroll
            for (int ci = 0; ci < 3; ++ci) {
                const float* xp = x + ((b*CIN + ci)*N_ + n)*T_ + t;
                xv[ci][0] = (t > 0)      ? xp[-1] : 0.f;
                xv[ci][1] = xp[0];
                xv[ci][2] = (t < T_ - 1) ? xp[1]  : 0.f;
            }
            float hs = 0.f, hd = 0.f;
#pragma unroll
            for (int c = 0; c < 64; ++c) {
                float acc = sTmb[c];
#pragma unroll
                for (int ci = 0; ci < 3; ++ci) {
                    const float* wr = &sTmw[(c*3 + ci)*3];
                    acc += wr[0]*xv[ci][0] + wr[1]*xv[ci][1] + wr[2]*xv[ci][2];
                }
                float xt = acc > 0.f ? acc : 0.01f*acc;
                hs += xt * sU[c];
                hd += xt * sV[c];
            }
            sHs[n] = hs; sHd[n] = hd;
        }
    }
    __syncthreads();

    int base = half ? 154 : 0;
    int cnt  = half ? 153 : 154;
#pragma unroll 1
    for (int r = w; r < cnt; r += 8) {
        int n = base + r;
        float hsv = sHs[n];
        const float* srow = sup + n*N_;
        float ww0, ww1, ww2, ww3, ww4;
        {
            float e;
            ww0 = 0.f;
            if (srow[lane] > 0.f) { e = hsv + sHd[lane]; e = e > 0.f ? e : 0.3f*e; ww0 = __expf(e); }
            ww1 = 0.f;
            if (srow[64 + lane] > 0.f) { e = hsv + sHd[64 + lane]; e = e > 0.f ? e : 0.3f*e; ww1 = __expf(e); }
            ww2 = 0.f;
            if (srow[128 + lane] > 0.f) { e = hsv + sHd[128 + lane]; e = e > 0.f ? e : 0.3f*e; ww2 = __expf(e); }
            ww3 = 0.f;
            if (srow[192 + lane] > 0.f) { e = hsv + sHd[192 + lane]; e = e > 0.f ? e : 0.3f*e; ww3 = __expf(e); }
            ww4 = 0.f;
            if (256 + lane < N_ && srow[256 + lane] > 0.f) {
                e = hsv + sHd[256 + lane]; e = e > 0.f ? e : 0.3f*e; ww4 = __expf(e);
            }
        }
        float asum = wave_sum(ww0 + ww1 + ww2 + ww3 + ww4);
        float inv = (asum > 0.f) ? 1.f/asum : 0.f;
        float* drow = Sc + (size_t)(bt*N_ + n)*N_;
        drow[lane]       = ww0*inv;
        drow[64 + lane]  = ww1*inv;
        drow[128 + lane] = ww2*inv;
        drow[192 + lane] = ww3*inv;
        if (256 + lane < N_) drow[256 + lane] = ww4*inv;
    }
}

// ---------------- kD: temporal attention TATT_1 ------------------------------
__global__ __launch_bounds__(256) void kD(const float* __restrict__ g1,
        const float* __restrict__ f2, const float* __restrict__ tb,
        const float* __restrict__ tv,
        const float* __restrict__ bng, const float* __restrict__ bnb,
        float* __restrict__ coefs, float* __restrict__ Tc,
        float* __restrict__ stats)
{
    __shared__ float g1s[T_][C];
    __shared__ float f2s[C][T_];
    __shared__ float lg[T_][T_];
    __shared__ float l2[T_][T_];
    int b = blockIdx.x, tid = threadIdx.x;
    if (tid == 0) { stats[2*b] = 0.f; stats[2*b + 1] = 0.f; }
    for (int idx = tid; idx < T_*C; idx += 256) {
        int t = idx / C, c = idx - t*C;
        g1s[t][c] = g1[(b*T_ + t)*C + c];
        int c2 = idx / T_, t2 = idx - c2*T_;
        f2s[c2][t2] = f2[(b*C + c2)*T_ + t2];
    }
    __syncthreads();
    for (int idx = tid; idx < T_*T_; idx += 256) {
        int t = idx / T_, q = idx - t*T_;
        float s = 0.f;
#pragma unroll
        for (int c = 0; c < C; ++c) s += g1s[t][c] * f2s[c][q];
        s += tb[t*T_ + q];
        lg[t][q] = 1.f / (1.f + expf(-s));
    }
    __syncthreads();
    const float bnscale = 0.99999500003749972f;  // 1/sqrt(1+1e-5)
    for (int idx = tid; idx < T_*T_; idx += 256) {
        int p = idx / T_, q = idx - p*T_;
        float s = 0.f;
#pragma unroll
        for (int t = 0; t < T_; ++t) s += tv[p*T_ + t] * lg[t][q];
        s = s * bnscale * bng[q] + bnb[q];
        if (q > p) s += -1e13f;   // causal mask
        l2[p][q] = s;
    }
    __syncthreads();
    if (tid < T_) {
        int p = tid;
        float mx = -3e38f;
#pragma unroll
        for (int q = 0; q < T_; ++q) mx = fmaxf(mx, l2[p][q]);
        float e[T_]; float sum = 0.f;
#pragma unroll
        for (int q = 0; q < T_; ++q) { e[q] = expf(l2[p][q] - mx); sum += e[q]; }
        float inv = 1.f / sum;
#pragma unroll
        for (int q = 0; q < T_; ++q) {
            float v = e[q] * inv;
            coefs[(b*T_ + p)*T_ + q] = v;
            Tc[(b*T_ + q)*T_ + p] = v;
        }
    }
}

// ---------------- kE: temporal mix + residual + LayerNorm --------------------
__device__ __forceinline__ void compute_y(int b, int n, int lane,
        const float* __restrict__ xg, const float cf[T_][T_],
        const float* __restrict__ x, const float* __restrict__ c1w,
        const float* __restrict__ c1b, float* y)
{
    float acc[T_];
#pragma unroll
    for (int q = 0; q < T_; ++q) acc[q] = 0.f;
#pragma unroll 1
    for (int l = 0; l < T_; ++l) {
        float xv = xg[(size_t)((b*T_ + l)*N_ + n)*64 + lane];
#pragma unroll
        for (int q = 0; q < T_; ++q) acc[q] += xv * cf[q][l];
    }
    float w0 = c1w[lane*3+0], w1 = c1w[lane*3+1], w2 = c1w[lane*3+2];
    float bb = c1b[lane];
    const float* xb0 = x + ((b*CIN + 0)*N_ + n)*T_;
    const float* xb1 = x + ((b*CIN + 1)*N_ + n)*T_;
    const float* xb2 = x + ((b*CIN + 2)*N_ + n)*T_;
#pragma unroll
    for (int q = 0; q < T_; ++q) {
        float xin = bb + w0*xb0[q] + w1*xb1[q] + w2*xb2[q];
        float v = acc[q];
        v = v > 0.f ? v : 0.01f*v;
        y[q] = v + xin;
    }
}

__global__ __launch_bounds__(256) void kE1(const float* __restrict__ xg,
        const float* __restrict__ coefs, const float* __restrict__ x,
        const float* __restrict__ c1w, const float* __restrict__ c1b,
        float* __restrict__ stats)
{
    __shared__ float cf[T_][T_];
    int b = blockIdx.y;
    for (int i = threadIdx.x; i < T_*T_; i += 256) ((float*)cf)[i] = coefs[b*T_*T_ + i];
    __syncthreads();
    int w = threadIdx.x >> 6, lane = threadIdx.x & 63;
    int n = blockIdx.x*4 + w;
    if (n >= N_) return;
    float y[T_];
    compute_y(b, n, lane, xg, cf, x, c1w, c1b, y);
    float s = 0.f, ss = 0.f;
#pragma unroll
    for (int q = 0; q < T_; ++q) { s += y[q]; ss += y[q]*y[q]; }
    s = wave_sum(s); ss = wave_sum(ss);
    if (lane == 0) { atomicAdd(&stats[2*b], s); atomicAdd(&stats[2*b + 1], ss); }
}

__global__ __launch_bounds__(256) void kE2(const float* __restrict__ xg,
        const float* __restrict__ coefs, const float* __restrict__ x,
        const float* __restrict__ c1w, const float* __restrict__ c1b,
        const float* __restrict__ stats, const float* __restrict__ lnw,
        const float* __restrict__ lnb, float* __restrict__ out)
{
    __shared__ float cf[T_][T_];
    int b = blockIdx.y;
    for (int i = threadIdx.x; i < T_*T_; i += 256) ((float*)cf)[i] = coefs[b*T_*T_ + i];
    __syncthreads();
    int w = threadIdx.x >> 6, lane = threadIdx.x & 63;
    int n = blockIdx.x*4 + w;
    if (n >= N_) return;
    float y[T_];
    compute_y(b, n, lane, xg, cf, x, c1w, c1b, y);
    float mu   = stats[2*b] * (1.f/CNT);
    float var  = stats[2*b + 1] * (1.f/CNT) - mu*mu;
    float rstd = rsqrtf(fmaxf(var, 0.f) + 1e-5f);
    int gi = (lane*N_ + n)*T_;
    float ov[T_];
#pragma unroll
    for (int q = 0; q < T_; ++q)
        ov[q] = (y[q] - mu)*rstd*lnw[gi + q] + lnb[gi + q];
    float* dst = out + ((size_t)(b*C + lane)*N_ + n)*T_;
#pragma unroll
    for (int j = 0; j < 6; ++j) {
        float4 v;
        v.x = ov[j*4+0]; v.y = ov[j*4+1]; v.z = ov[j*4+2]; v.w = ov[j*4+3];
        ((float4*)dst)[j] = v;
    }
}

extern "C" void kernel_launch(void* const* d_in, const int* in_sizes, int n_in,
                              void* d_out, int out_size, void* d_ws, size_t ws_size,
                              hipStream_t stream)
{
    const float* x   = (const float*)d_in[0];
    const float* sup = (const float*)d_in[1];
    const float* c1w = (const float*)d_in[2];
    const float* c1b = (const float*)d_in[3];
    const float* tmw = (const float*)d_in[4];
    const float* tmb = (const float*)d_in[5];
    const float* W1  = (const float*)d_in[6];
    const float* a1s = (const float*)d_in[7];
    const float* a1d = (const float*)d_in[8];
    const float* W2  = (const float*)d_in[9];
    const float* a2s = (const float*)d_in[10];
    const float* a2d = (const float*)d_in[11];
    const float* t1w = (const float*)d_in[12];
    const float* t2w = (const float*)d_in[13];
    const float* tw  = (const float*)d_in[14];
    const float* tb  = (const float*)d_in[15];
    const float* tv  = (const float*)d_in[16];
    const float* bng = (const float*)d_in[17];
    const float* bnb = (const float*)d_in[18];
    const float* lnw = (const float*)d_in[19];
    const float* lnb = (const float*)d_in[20];

    float* out = (float*)d_out;
    float* Sc  = out + OUT_ELEMS;               // final S_coef region (f32)
    float* Tc  = Sc + (size_t)S_ELEMS;          // final T_coef region (f32)

    // ALL scratch lives inside the Sc region (overwritten last by kSc).
    // d_ws is never touched.
    float* xg    = Sc;                          // OUT_ELEMS f32 (filt, then gated)
    float* f1    = Sc + (size_t)OUT_ELEMS;      // ROWS f32
    float* f2    = f1 + ROWS;                   // BZ*C*T_ f32
    float* g1    = f2 + BZ*C*T_;                // BT*C f32
    float* coefs = g1 + BT*C;                   // BZ*T_*T_ f32
    float* stats = coefs + BZ*T_*T_;            // 32 f32
    u32*   adjm  = (u32*)(stats + 32);          // 3200 u32 adjacency bitmask
    float* gbuf  = (float*)(adjm + 3200);       // OUT_ELEMS f32 (gate logits)

    kAdjPre<<<7, 512, 0, stream>>>(sup, adjm);
    kGAT2<<<dim3(BT, 2), 512, 0, stream>>>(x, tmw, tmb, W1, a1s, a1d,
                                           W2, a2s, a2d, adjm, xg, gbuf);
    kComb<<<BT, 512, 0, stream>>>(xg, gbuf, t1w, t2w, tw, f1, f2, g1);
    kD<<<BZ, 256, 0, stream>>>(g1, f2, tb, tv, bng, bnb, coefs, Tc, stats);
    kE1<<<dim3(77, BZ), 256, 0, stream>>>(xg, coefs, x, c1w, c1b, stats);
    kE2<<<dim3(77, BZ), 256, 0, stream>>>(xg, coefs, x, c1w, c1b, stats, lnw, lnb, out);
    kSc<<<dim3(2, BT), 512, 0, stream>>>(x, sup, tmw, tmb, W1, a1s, a1d, Sc);
}

// Round 9
// 569.449 us; speedup vs baseline: 1.6358x; 1.0380x over previous
//
#include <hip/hip_runtime.h>

typedef unsigned short u16;
typedef unsigned int u32;
typedef __attribute__((ext_vector_type(8))) short bf16x8;
typedef __attribute__((ext_vector_type(4))) float f32x4;

#define BZ 16
#define CIN 3
#define C 64
#define N_ 307
#define T_ 24
#define BT (BZ*T_)          // 384
#define ROWS (BT*N_)        // 117888
#define CNT (C*N_*T_)       // 471552

#define OUT_ELEMS 7544832
#define S_ELEMS   36191616

#define HSTRIDE 344         // u16 stride of sHT rows: 688 B = 43*16 (16B-aligned b128)

__device__ __forceinline__ u16 f2b(float v) {
    union { float f; unsigned u; } x; x.f = v;
    unsigned u = x.u;
    unsigned rb = (u >> 16) & 1u;
    u += 0x7fffu + rb;
    return (u16)(u >> 16);
}
__device__ __forceinline__ float wave_sum(float v) {
#pragma unroll
    for (int m = 32; m > 0; m >>= 1) v += __shfl_xor(v, m);
    return v;
}

// ---- kAdjPre: bit-pack adjacency (sup > 0) into adjm[320][10] u32 ----------
__global__ __launch_bounds__(512) void kAdjPre(const float* __restrict__ sup,
        u32* __restrict__ adjm)
{
    int idx = blockIdx.x*512 + threadIdx.x;   // word index: n*10 + kw
    if (idx >= 3200) return;
    int n = idx / 10, kw = idx - n*10;
    u32 bits = 0;
    if (n < N_) {
        const float* row = sup + n*N_ + kw*32;
        int lim = N_ - kw*32; if (lim > 32) lim = 32;
        for (int j = 0; j < lim; ++j)
            if (row[j] > 0.f) bits |= (1u << j);
    }
    adjm[idx] = bits;
}

// ===== kGAT2: both GATs in ONE dispatch, grid (BT, 2) ========================
__global__ __launch_bounds__(512, 2) void kGAT2(
        const float* __restrict__ x,
        const float* __restrict__ tmw, const float* __restrict__ tmb,
        const float* __restrict__ W1, const float* __restrict__ a1s,
        const float* __restrict__ a1d,
        const float* __restrict__ W2, const float* __restrict__ a2s,
        const float* __restrict__ a2d,
        const u32* __restrict__ adjm,
        float* __restrict__ fbuf, float* __restrict__ gbuf)
{
    __shared__ u16 sHT[64*HSTRIDE];  // 44 KB, h transposed [f][m] bf16
    __shared__ float sXA[3200];      // 12.8 KB: x window -> adj bitmask
    __shared__ float sTmw[576];
    __shared__ float sTmb[64];
    __shared__ float sU[64];
    __shared__ float sV[64];
    __shared__ float sHs[320];
    __shared__ float sHd[320];

    int bt = blockIdx.x;
    int gy = blockIdx.y;
    int b = bt / T_, t = bt - b * T_;
    int tid = threadIdx.x;
    int w = tid >> 6, lane = tid & 63;
    int l15 = lane & 15, quad = lane >> 4;

    const float* W   = gy ? W2  : W1;
    const float* asp = gy ? a2s : a1s;
    const float* adp = gy ? a2d : a1d;
    float* dst       = gy ? gbuf : fbuf;

    // ---- stage x window + weights ----
    for (int i = tid; i < 2880; i += 512) {
        int k = i % 3; int rest = i / 3;
        int n = rest % 320; int ci = rest / 320;
        int tt = t - 1 + k;
        float v = 0.f;
        if (n < N_ && tt >= 0 && tt < T_)
            v = x[((b*CIN + ci)*N_ + n)*T_ + tt];
        sXA[i] = v;
    }
    for (int i = tid; i < 576; i += 512) sTmw[i] = tmw[i];
    if (tid < 64) {
        sTmb[tid] = tmb[tid];
        // u[c] = W[c]·a_src, v[c] = W[c]·a_dst (f32)
        float u = 0.f, v = 0.f;
#pragma unroll
        for (int f4 = 0; f4 < 16; ++f4) {
            float4 wr = ((const float4*)(W + tid*64))[f4];
            float4 s4 = ((const float4*)asp)[f4];
            float4 d4 = ((const float4*)adp)[f4];
            u += wr.x*s4.x + wr.y*s4.y + wr.z*s4.z + wr.w*s4.w;
            v += wr.x*d4.x + wr.y*d4.y + wr.z*d4.z + wr.w*d4.w;
        }
        sU[tid] = u; sV[tid] = v;
    }

    // W as MFMA B-frags: wf[kk][nt][j] = W[kk*32+quad*8+j][nt*16+l15]
    bf16x8 wf[2][4];
#pragma unroll
    for (int kk = 0; kk < 2; ++kk)
#pragma unroll
    for (int nt = 0; nt < 4; ++nt) {
        bf16x8 a;
#pragma unroll
        for (int j = 0; j < 8; ++j)
            a[j] = (short)f2b(W[(kk*32 + quad*8 + j)*64 + nt*16 + l15]);
        wf[kk][nt] = a;
    }
    __syncthreads();

    // ---- phase 1: tconv + h via MFMA; sHT, sHs, sHd ----
#pragma unroll 1
    for (int mt = w; mt < 20; mt += 8) {
        int row = mt*16 + l15;
        float xt[16];
#pragma unroll
        for (int half = 0; half < 2; ++half) {
#pragma unroll
            for (int j = 0; j < 8; ++j) {
                int c = half*32 + quad*8 + j;
                float acc = sTmb[c];
#pragma unroll
                for (int ci = 0; ci < 3; ++ci) {
                    const float* xr = &sXA[(ci*320 + row)*3];
                    const float* wr = &sTmw[(c*3 + ci)*3];
                    acc += wr[0]*xr[0] + wr[1]*xr[1] + wr[2]*xr[2];
                }
                xt[half*8 + j] = acc > 0.f ? acc : 0.01f*acc;
            }
        }
        // hs/hd: f32 dot with u,v then cross-quad reduce
        float ps = 0.f, pd = 0.f;
#pragma unroll
        for (int j = 0; j < 8; ++j) {
            ps += xt[j]*sU[quad*8 + j] + xt[8 + j]*sU[32 + quad*8 + j];
            pd += xt[j]*sV[quad*8 + j] + xt[8 + j]*sV[32 + quad*8 + j];
        }
        ps += __shfl_xor(ps, 16); ps += __shfl_xor(ps, 32);
        pd += __shfl_xor(pd, 16); pd += __shfl_xor(pd, 32);
        if (quad == 0 && row < N_) { sHs[row] = ps; sHd[row] = pd; }
        // A-frags + h MFMA
        bf16x8 a0, a1;
#pragma unroll
        for (int j = 0; j < 8; ++j) {
            a0[j] = (short)f2b(xt[j]);
            a1[j] = (short)f2b(xt[8 + j]);
        }
        f32x4 hacc[4];
#pragma unroll
        for (int nt = 0; nt < 4; ++nt) {
            f32x4 z = {0.f, 0.f, 0.f, 0.f};
            z = __builtin_amdgcn_mfma_f32_16x16x32_bf16(a0, wf[0][nt], z, 0, 0, 0);
            z = __builtin_amdgcn_mfma_f32_16x16x32_bf16(a1, wf[1][nt], z, 0, 0, 0);
            hacc[nt] = z;
        }
        // write h^T: f = nt*16+l15, m = mt*16+quad*4+reg (packed u32)
#pragma unroll
        for (int nt = 0; nt < 4; ++nt) {
            u32 w0 = (u32)f2b(hacc[nt][0]) | ((u32)f2b(hacc[nt][1]) << 16);
            u32 w1 = (u32)f2b(hacc[nt][2]) | ((u32)f2b(hacc[nt][3]) << 16);
            u32* dp = (u32*)(sHT + (nt*16 + l15)*HSTRIDE + mt*16 + quad*4);
            dp[0] = w0; dp[1] = w1;
        }
    }
    if (tid < 13) { sHs[307+tid] = -700.f; sHd[307+tid] = -700.f; }
    __syncthreads();   // phase 1 done with sXA

    // ---- adj bitmask into LDS (overwrites x window) ----
    u32* sAdj = (u32*)sXA;
    for (int i = tid; i < 3200; i += 512) sAdj[i] = adjm[i];
    __syncthreads();

    // ---- phase 2: A-frag generation + MFMA att@h; write normalized out ----
#pragma unroll 1
    for (int mt = w; mt < 20; mt += 8) {
        int n = mt*16 + l15;                 // A row owned by this lane
        float hsv = sHs[n];
        float asum = 0.f;
        bf16x8 af[10];
#pragma unroll
        for (int ks = 0; ks < 10; ++ks) {
            u32 aw = sAdj[n*10 + ks] >> (quad*8);
            int m0 = ks*32 + quad*8;
            bf16x8 a;
#pragma unroll
            for (int j = 0; j < 8; ++j) {
                float e = hsv + sHd[m0 + j];
                e = e > 0.f ? e : 0.3f*e;
                float ww = ((aw >> j) & 1u) ? __expf(e) : 0.f;
                asum += ww;
                a[j] = (short)f2b(ww);
            }
            af[ks] = a;
        }
        asum += __shfl_xor(asum, 16);
        asum += __shfl_xor(asum, 32);
        float invv = (asum > 0.f) ? 1.f/asum : 0.f;

#pragma unroll 1
        for (int nt = 0; nt < 4; ++nt) {
            f32x4 acc = {0.f, 0.f, 0.f, 0.f};
            const u16* bbase = sHT + (nt*16 + l15)*HSTRIDE;
#pragma unroll
            for (int ks = 0; ks < 10; ++ks) {
                bf16x8 bfrag = *(const bf16x8*)(bbase + ks*32 + quad*8);
                acc = __builtin_amdgcn_mfma_f32_16x16x32_bf16(af[ks], bfrag, acc, 0, 0, 0);
            }
            int c = nt*16 + l15;
#pragma unroll
            for (int reg = 0; reg < 4; ++reg) {
                int n2 = mt*16 + quad*4 + reg;       // C-layout row
                float inv2 = __shfl(invv, quad*4 + reg);
                float a = acc[reg] * inv2;
                if (n2 < N_) dst[(size_t)(bt*N_ + n2)*64 + c] = a;
            }
        }
    }
}

// ===== kComb: xv = sigmoid(gate)*lrelu(filt) in-place; f2, g1 (float4) ======
// lane = 4 channels (li*4..+3), wave covers 4 rows/iter; f1 global was dead.
__global__ __launch_bounds__(512) void kComb(
        float* __restrict__ xg, const float* __restrict__ gbuf,
        const float* __restrict__ t1w, const float* __restrict__ t2w,
        const float* __restrict__ tw,
        float* __restrict__ f2, float* __restrict__ g1)
{
    __shared__ float sF1[320];
    __shared__ float sRedF2[8][64][4];   // 8 KB
    __shared__ float sRed[8][64];
    __shared__ float sT1[64];

    int bt = blockIdx.x;
    int b = bt / T_, t = bt - b * T_;
    int tid = threadIdx.x;
    int w = tid >> 6, lane = tid & 63;
    int nr = lane >> 4, li = lane & 15;

    if (tid < 64) sT1[tid] = t1w[tid];
    if (tid < 13) sF1[307 + tid] = 0.f;
    __syncthreads();

    float4 t14 = ((const float4*)sT1)[li];
    float4 f2v = {0.f, 0.f, 0.f, 0.f};

#pragma unroll 1
    for (int k = 0; k < 10; ++k) {
        int n = k*32 + w*4 + nr;
        if (n < N_) {
            size_t idx = (size_t)(bt*N_ + n)*64 + li*4;
            float4 f = *(const float4*)(xg + idx);
            float4 g = *(const float4*)(gbuf + idx);
            float4 xv;
            xv.x = (1.f/(1.f+__expf(-g.x))) * (f.x > 0.f ? f.x : 0.01f*f.x);
            xv.y = (1.f/(1.f+__expf(-g.y))) * (f.y > 0.f ? f.y : 0.01f*f.y);
            xv.z = (1.f/(1.f+__expf(-g.z))) * (f.z > 0.f ? f.z : 0.01f*f.z);
            xv.w = (1.f/(1.f+__expf(-g.w))) * (f.w > 0.f ? f.w : 0.01f*f.w);
            *(float4*)(xg + idx) = xv;
            float p = xv.x*t14.x + xv.y*t14.y + xv.z*t14.z + xv.w*t14.w;
            p += __shfl_xor(p, 1); p += __shfl_xor(p, 2);
            p += __shfl_xor(p, 4); p += __shfl_xor(p, 8);
            if (li == 0) sF1[n] = p;
            float t2v = t2w[n];
            f2v.x += xv.x*t2v; f2v.y += xv.y*t2v;
            f2v.z += xv.z*t2v; f2v.w += xv.w*t2v;
        }
    }
    sRedF2[w][lane][0] = f2v.x; sRedF2[w][lane][1] = f2v.y;
    sRedF2[w][lane][2] = f2v.z; sRedF2[w][lane][3] = f2v.w;
    __syncthreads();
    if (tid < 64) {
        int comp = tid & 3, li2 = tid >> 2;
        float s = 0.f;
#pragma unroll
        for (int ww = 0; ww < 8; ++ww)
#pragma unroll
        for (int g2 = 0; g2 < 4; ++g2)
            s += sRedF2[ww][g2*16 + li2][comp];
        f2[(b*C + tid)*T_ + t] = s;
    }
    // g1[bt][c] = sum_n sF1[n] * tw[n][c], spread over 8 waves
    float gacc = 0.f;
    int n0 = w*40, n1 = n0 + 40; if (n1 > N_) n1 = N_;
    for (int n = n0; n < n1; ++n) gacc += sF1[n] * tw[n*64 + lane];
    sRed[w][lane] = gacc;
    __syncthreads();
    if (tid < 64) {
        float s = sRed[0][tid];
#pragma unroll
        for (int ww = 1; ww < 8; ++ww) s += sRed[ww][tid];
        g1[bt*64 + tid] = s;
    }
}

// ===== kSc: recompute GAT1 softmax and write S_coef (runs LAST) ==============
__global__ __launch_bounds__(512) void kSc(
        const float* __restrict__ x, const float* __restrict__ sup,
        const float* __restrict__ tmw, const float* __restrict__ tmb,
        const float* __restrict__ W, const float* __restrict__ asp,
        const float* __restrict__ adp, float* __restrict__ Sc)
{
    __shared__ float sHs[320];
    __shared__ float sHd[320];
    __shared__ float sU[64], sV[64];
    __shared__ float sTmw[576];
    __shared__ float sTmb[64];

    int half = blockIdx.x;
    int bt = blockIdx.y;
    int b = bt / T_, t = bt - b * T_;
    int tid = threadIdx.x;
    int w = tid >> 6, lane = tid & 63;

    for (int i = tid; i < 576; i += 512) sTmw[i] = tmw[i];
    if (tid < 64) {
        sTmb[tid] = tmb[tid];
        float u = 0.f, v = 0.f;
#pragma unroll
        for (int f4 = 0; f4 < 16; ++f4) {
            float4 wr = ((const float4*)(W + tid*64))[f4];
            float4 s4 = ((const float4*)asp)[f4];
            float4 d4 = ((const float4*)adp)[f4];
            u += wr.x*s4.x + wr.y*s4.y + wr.z*s4.z + wr.w*s4.w;
            v += wr.x*d4.x + wr.y*d4.y + wr.z*d4.z + wr.w*d4.w;
        }
        sU[tid] = u; sV[tid] = v;
    }
    __syncthreads();

    if (tid < 320) {
        int n = tid;
        if (n >= N_) { sHs[n] = -700.f; sHd[n] = -700.f; }
        else {
            float xv[3][3];
#pragma unroll
            for (int ci = 0; ci < 3; ++ci) {
                const float* xp = x + ((b*CIN + ci)*N_ + n)*T_ + t;
                xv[ci][0] = (t > 0)      ? xp[-1] : 0.f;
                xv[ci][1] = xp[0];
                xv[ci][2] = (t < T_ - 1) ? xp[1]  : 0.f;
            }
            float hs = 0.f, hd = 0.f;
#pragma unroll
            for (int c = 0; c < 64; ++c) {
                float acc = sTmb[c];
#pragma unroll
                for (int ci = 0; ci < 3; ++ci) {
                    const float* wr = &sTmw[(c*3 + ci)*3];
                    acc += wr[0]*xv[ci][0] + wr[1]*xv[ci][1] + wr[2]*xv[ci][2];
                }
                float xt = acc > 0.f ? acc : 0.01f*acc;
                hs += xt * sU[c];
                hd += xt * sV[c];
            }
            sHs[n] = hs; sHd[n] = hd;
        }
    }
    __syncthreads();

    int base = half ? 154 : 0;
    int cnt  = half ? 153 : 154;
#pragma unroll 1
    for (int r = w; r < cnt; r += 8) {
        int n = base + r;
        float hsv = sHs[n];
        const float* srow = sup + n*N_;
        float ww0, ww1, ww2, ww3, ww4;
        {
            float e;
            ww0 = 0.f;
            if (srow[lane] > 0.f) { e = hsv + sHd[lane]; e = e > 0.f ? e : 0.3f*e; ww0 = __expf(e); }
            ww1 = 0.f;
            if (srow[64 + lane] > 0.f) { e = hsv + sHd[64 + lane]; e = e > 0.f ? e : 0.3f*e; ww1 = __expf(e); }
            ww2 = 0.f;
            if (srow[128 + lane] > 0.f) { e = hsv + sHd[128 + lane]; e = e > 0.f ? e : 0.3f*e; ww2 = __expf(e); }
            ww3 = 0.f;
            if (srow[192 + lane] > 0.f) { e = hsv + sHd[192 + lane]; e = e > 0.f ? e : 0.3f*e; ww3 = __expf(e); }
            ww4 = 0.f;
            if (256 + lane < N_ && srow[256 + lane] > 0.f) {
                e = hsv + sHd[256 + lane]; e = e > 0.f ? e : 0.3f*e; ww4 = __expf(e);
            }
        }
        float asum = wave_sum(ww0 + ww1 + ww2 + ww3 + ww4);
        float inv = (asum > 0.f) ? 1.f/asum : 0.f;
        float* drow = Sc + (size_t)(bt*N_ + n)*N_;
        drow[lane]       = ww0*inv;
        drow[64 + lane]  = ww1*inv;
        drow[128 + lane] = ww2*inv;
        drow[192 + lane] = ww3*inv;
        if (256 + lane < N_) drow[256 + lane] = ww4*inv;
    }
}

// ---------------- kD: temporal attention TATT_1 ------------------------------
__global__ __launch_bounds__(256) void kD(const float* __restrict__ g1,
        const float* __restrict__ f2, const float* __restrict__ tb,
        const float* __restrict__ tv,
        const float* __restrict__ bng, const float* __restrict__ bnb,
        float* __restrict__ coefs, float* __restrict__ Tc,
        float* __restrict__ stats)
{
    __shared__ float g1s[T_][C];
    __shared__ float f2s[C][T_];
    __shared__ float lg[T_][T_];
    __shared__ float l2[T_][T_];
    int b = blockIdx.x, tid = threadIdx.x;
    if (tid == 0) { stats[2*b] = 0.f; stats[2*b + 1] = 0.f; }
    for (int idx = tid; idx < T_*C; idx += 256) {
        int t = idx / C, c = idx - t*C;
        g1s[t][c] = g1[(b*T_ + t)*C + c];
        int c2 = idx / T_, t2 = idx - c2*T_;
        f2s[c2][t2] = f2[(b*C + c2)*T_ + t2];
    }
    __syncthreads();
    for (int idx = tid; idx < T_*T_; idx += 256) {
        int t = idx / T_, q = idx - t*T_;
        float s = 0.f;
#pragma unroll
        for (int c = 0; c < C; ++c) s += g1s[t][c] * f2s[c][q];
        s += tb[t*T_ + q];
        lg[t][q] = 1.f / (1.f + expf(-s));
    }
    __syncthreads();
    const float bnscale = 0.99999500003749972f;  // 1/sqrt(1+1e-5)
    for (int idx = tid; idx < T_*T_; idx += 256) {
        int p = idx / T_, q = idx - p*T_;
        float s = 0.f;
#pragma unroll
        for (int t = 0; t < T_; ++t) s += tv[p*T_ + t] * lg[t][q];
        s = s * bnscale * bng[q] + bnb[q];
        if (q > p) s += -1e13f;   // causal mask
        l2[p][q] = s;
    }
    __syncthreads();
    if (tid < T_) {
        int p = tid;
        float mx = -3e38f;
#pragma unroll
        for (int q = 0; q < T_; ++q) mx = fmaxf(mx, l2[p][q]);
        float e[T_]; float sum = 0.f;
#pragma unroll
        for (int q = 0; q < T_; ++q) { e[q] = expf(l2[p][q] - mx); sum += e[q]; }
        float inv = 1.f / sum;
#pragma unroll
        for (int q = 0; q < T_; ++q) {
            float v = e[q] * inv;
            coefs[(b*T_ + p)*T_ + q] = v;
            Tc[(b*T_ + q)*T_ + p] = v;
        }
    }
}

// ---------------- kE: temporal mix + residual + LayerNorm --------------------
__device__ __forceinline__ void compute_y(int b, int n, int lane,
        const float* __restrict__ xg, const float cf[T_][T_],
        const float* __restrict__ x, const float* __restrict__ c1w,
        const float* __restrict__ c1b, float* y)
{
    float acc[T_];
#pragma unroll
    for (int q = 0; q < T_; ++q) acc[q] = 0.f;
#pragma unroll 1
    for (int l = 0; l < T_; ++l) {
        float xv = xg[(size_t)((b*T_ + l)*N_ + n)*64 + lane];
#pragma unroll
        for (int q = 0; q < T_; ++q) acc[q] += xv * cf[q][l];
    }
    float w0 = c1w[lane*3+0], w1 = c1w[lane*3+1], w2 = c1w[lane*3+2];
    float bb = c1b[lane];
    const float* xb0 = x + ((b*CIN + 0)*N_ + n)*T_;
    const float* xb1 = x + ((b*CIN + 1)*N_ + n)*T_;
    const float* xb2 = x + ((b*CIN + 2)*N_ + n)*T_;
#pragma unroll
    for (int q = 0; q < T_; ++q) {
        float xin = bb + w0*xb0[q] + w1*xb1[q] + w2*xb2[q];
        float v = acc[q];
        v = v > 0.f ? v : 0.01f*v;
        y[q] = v + xin;
    }
}

// kE1: compute y once, write to ybuf ([b][n][q][c] layout), accumulate stats
__global__ __launch_bounds__(256) void kE1(const float* __restrict__ xg,
        const float* __restrict__ coefs, const float* __restrict__ x,
        const float* __restrict__ c1w, const float* __restrict__ c1b,
        float* __restrict__ ybuf, float* __restrict__ stats)
{
    __shared__ float cf[T_][T_];
    int b = blockIdx.y;
    for (int i = threadIdx.x; i < T_*T_; i += 256) ((float*)cf)[i] = coefs[b*T_*T_ + i];
    __syncthreads();
    int w = threadIdx.x >> 6, lane = threadIdx.x & 63;
    int n = blockIdx.x*4 + w;
    if (n >= N_) return;
    float y[T_];
    compute_y(b, n, lane, xg, cf, x, c1w, c1b, y);
    float* yb = ybuf + (size_t)(b*N_ + n)*24*64;
#pragma unroll
    for (int q = 0; q < T_; ++q) yb[q*64 + lane] = y[q];
    float s = 0.f, ss = 0.f;
#pragma unroll
    for (int q = 0; q < T_; ++q) { s += y[q]; ss += y[q]*y[q]; }
    s = wave_sum(s); ss = wave_sum(ss);
    if (lane == 0) { atomicAdd(&stats[2*b], s); atomicAdd(&stats[2*b + 1], ss); }
}

// kE2: pure stream - read y, normalize, write out (no recompute)
__global__ __launch_bounds__(256) void kE2(const float* __restrict__ ybuf,
        const float* __restrict__ stats, const float* __restrict__ lnw,
        const float* __restrict__ lnb, float* __restrict__ out)
{
    int b = blockIdx.y;
    int w = threadIdx.x >> 6, lane = threadIdx.x & 63;
    int n = blockIdx.x*4 + w;
    if (n >= N_) return;
    const float* yb = ybuf + (size_t)(b*N_ + n)*24*64;
    float y[T_];
#pragma unroll
    for (int q = 0; q < T_; ++q) y[q] = yb[q*64 + lane];
    float mu   = stats[2*b] * (1.f/CNT);
    float var  = stats[2*b + 1] * (1.f/CNT) - mu*mu;
    float rstd = rsqrtf(fmaxf(var, 0.f) + 1e-5f);
    int gi = (lane*N_ + n)*T_;
    float ov[T_];
#pragma unroll
    for (int q = 0; q < T_; ++q)
        ov[q] = (y[q] - mu)*rstd*lnw[gi + q] + lnb[gi + q];
    float* dst = out + ((size_t)(b*C + lane)*N_ + n)*T_;
#pragma unroll
    for (int j = 0; j < 6; ++j) {
        float4 v;
        v.x = ov[j*4+0]; v.y = ov[j*4+1]; v.z = ov[j*4+2]; v.w = ov[j*4+3];
        ((float4*)dst)[j] = v;
    }
}

extern "C" void kernel_launch(void* const* d_in, const int* in_sizes, int n_in,
                              void* d_out, int out_size, void* d_ws, size_t ws_size,
                              hipStream_t stream)
{
    const float* x   = (const float*)d_in[0];
    const float* sup = (const float*)d_in[1];
    const float* c1w = (const float*)d_in[2];
    const float* c1b = (const float*)d_in[3];
    const float* tmw = (const float*)d_in[4];
    const float* tmb = (const float*)d_in[5];
    const float* W1  = (const float*)d_in[6];
    const float* a1s = (const float*)d_in[7];
    const float* a1d = (const float*)d_in[8];
    const float* W2  = (const float*)d_in[9];
    const float* a2s = (const float*)d_in[10];
    const float* a2d = (const float*)d_in[11];
    const float* t1w = (const float*)d_in[12];
    const float* t2w = (const float*)d_in[13];
    const float* tw  = (const float*)d_in[14];
    const float* tb  = (const float*)d_in[15];
    const float* tv  = (const float*)d_in[16];
    const float* bng = (const float*)d_in[17];
    const float* bnb = (const float*)d_in[18];
    const float* lnw = (const float*)d_in[19];
    const float* lnb = (const float*)d_in[20];

    float* out = (float*)d_out;
    float* Sc  = out + OUT_ELEMS;               // final S_coef region (f32)
    float* Tc  = Sc + (size_t)S_ELEMS;          // final T_coef region (f32)

    // ALL scratch lives inside the Sc region (overwritten last by kSc).
    // d_ws is never touched.
    float* xg    = Sc;                          // OUT_ELEMS f32 (filt, then gated)
    float* f1    = Sc + (size_t)OUT_ELEMS;      // ROWS f32 (unused; layout keep)
    float* f2    = f1 + ROWS;                   // BZ*C*T_ f32
    float* g1    = f2 + BZ*C*T_;                // BT*C f32
    float* coefs = g1 + BT*C;                   // BZ*T_*T_ f32
    float* stats = coefs + BZ*T_*T_;            // 32 f32
    u32*   adjm  = (u32*)(stats + 32);          // 3200 u32 adjacency bitmask
    float* gbuf  = (float*)(adjm + 3200);       // OUT_ELEMS f32 (gate logits)
    float* ybuf  = gbuf + (size_t)OUT_ELEMS;    // OUT_ELEMS f32 (pre-LN y)

    kAdjPre<<<7, 512, 0, stream>>>(sup, adjm);
    kGAT2<<<dim3(BT, 2), 512, 0, stream>>>(x, tmw, tmb, W1, a1s, a1d,
                                           W2, a2s, a2d, adjm, xg, gbuf);
    kComb<<<BT, 512, 0, stream>>>(xg, gbuf, t1w, t2w, tw, f2, g1);
    kD<<<BZ, 256, 0, stream>>>(g1, f2, tb, tv, bng, bnb, coefs, Tc, stats);
    kE1<<<dim3(77, BZ), 256, 0, stream>>>(xg, coefs, x, c1w, c1b, ybuf, stats);
    kE2<<<dim3(77, BZ), 256, 0, stream>>>(ybuf, stats, lnw, lnb, out);
    kSc<<<dim3(2, BT), 512, 0, stream>>>(x, sup, tmw, tmb, W1, a1s, a1d, Sc);
}